// Round 1
// 1032.726 us; speedup vs baseline: 1.1495x; 1.1495x over previous
//
#include <hip/hip_runtime.h>
#include <hip/hip_fp16.h>
#include <cstddef>

#define Wn 12
#define Nn 20000
#define Cn 64
#define En 320000
#define OFFS_STRIDE 20032

typedef _Float16 h4v __attribute__((ext_vector_type(4)));
typedef _Float16 h8v __attribute__((ext_vector_type(8)));
typedef float    f4v __attribute__((ext_vector_type(4)));

__device__ __forceinline__ float elu_f(float v) {
    return v > 0.f ? v : (expf(v) - 1.f);
}

// ---------------------------------------------------------------------------
// Weight prep: pack all 4 kernel sizes (sig+gate) into MFMA B-fragment order.
// Layout (halfs): groups g=0..3 at bases {0,2048,8192,18432}; within a group:
//   [sg in {sig,gate}][s = (dw+g)*2 + ic_half][lane 0..63][j 0..7]
// where the 8 halfs at (lane,j) are B[k][col]: col = lane&15 (oc in group),
// k = (lane>>4)*8 + j within the 32-slice, ic = ic_half*32 + k, t = dw+g.
// One ds_read_b128 per B fragment in the main kernel, bank-linear.
// ---------------------------------------------------------------------------
__global__ __launch_bounds__(256) void wprep_kernel(
    const float* __restrict__ sw1, const float* __restrict__ gw1,
    const float* __restrict__ sw3, const float* __restrict__ gw3,
    const float* __restrict__ sw5, const float* __restrict__ gw5,
    const float* __restrict__ sw7, const float* __restrict__ gw7,
    __half* __restrict__ dst)
{
    const int i = blockIdx.x * 256 + threadIdx.x;   // 32768 total
    if (i >= 32768) return;
    const int j    = i & 7;
    const int lane = (i >> 3) & 63;
    const int slot = i >> 9;                        // 0..63
    int g, loc;
    if (slot < 4)       { g = 0; loc = slot; }
    else if (slot < 16) { g = 1; loc = slot - 4; }
    else if (slot < 36) { g = 2; loc = slot - 16; }
    else                { g = 3; loc = slot - 36; }
    const int k   = 2 * g + 1;
    const int nks = 2 * k;                          // k-steps per path
    const int sg  = (loc >= nks) ? 1 : 0;          // 0 = sig, 1 = gate
    const int s   = loc - sg * nks;
    const int t   = s >> 1;                         // tap 0..k-1
    const int ih  = s & 1;                          // ic half
    const int oc  = lane & 15;
    const int ic  = ih * 32 + (lane >> 4) * 8 + j;
    const float* src;
    switch (g * 2 + sg) {
      case 0: src = sw1; break; case 1: src = gw1; break;
      case 2: src = sw3; break; case 3: src = gw3; break;
      case 4: src = sw5; break; case 5: src = gw5; break;
      case 6: src = sw7; break; default: src = gw7; break;
    }
    dst[i] = __float2half(src[(oc * 64 + ic) * k + t]);
}

// ---------------------------------------------------------------------------
// One oc-group of the inception conv via MFMA. 4 waves; wave wv owns windows
// w = wv*3 + {0,1,2}. Per (dw, ic_half): 2 B-frag loads (sig,gate) + 3 A-frag
// loads + 6 independent MFMAs (no dependent-chain stalls even at 1 wave/SIMD).
// Boundary windows skip out-of-range dw (wave-uniform branch).
// ---------------------------------------------------------------------------
template<int G>
__device__ __forceinline__ void mfma_group(
    const __half* __restrict__ wTg,    // global fragment-packed weights, group G
    __half* __restrict__ wsh,
    const __half* __restrict__ xsh,
    const float* __restrict__ sb, const float* __restrict__ gb,
    float* __restrict__ h, int nb, int tid)
{
    constexpr int NKS = 2 * (2 * G + 1);
    // stage this group's fragments: (2G+1)*4096 B, contiguous copy
    {
        const uint4* src = (const uint4*)wTg;
        uint4* dst = (uint4*)wsh;
        #pragma unroll
        for (int i = 0; i < 2 * G + 1; ++i)
            dst[tid + i * 256] = src[tid + i * 256];
    }
    __syncthreads();

    const int lane = tid & 63;
    const int wv   = tid >> 6;                 // 0..3
    const int node16 = lane & 15;
    // lane-dependent part of the A-frag LDS byte offset, per ic-half
    const int abase = node16 * 128;
    const int swz   = (lane & 7) << 4;
    const int aoff0 = abase + ((0  + (lane >> 4) * 16) ^ swz);
    const int aoff1 = abase + ((64 + (lane >> 4) * 16) ^ swz);

    f4v accS[3], accG[3];
    #pragma unroll
    for (int m = 0; m < 3; ++m) {
        accS[m] = (f4v){0.f, 0.f, 0.f, 0.f};
        accG[m] = (f4v){0.f, 0.f, 0.f, 0.f};
    }

    #pragma unroll
    for (int s2 = 0; s2 < 2 * G + 1; ++s2) {   // dw = s2 - G
        const int dw = s2 - G;
        #pragma unroll
        for (int ih = 0; ih < 2; ++ih) {
            const int s = s2 * 2 + ih;
            const h8v bs = *(const h8v*)&wsh[(s * 64 + lane) * 8];
            const h8v bg = *(const h8v*)&wsh[((NKS + s) * 64 + lane) * 8];
            const int laneoff = ih ? aoff1 : aoff0;
            #pragma unroll
            for (int m = 0; m < 3; ++m) {
                const int w  = wv * 3 + m;
                const int wp = w + dw;
                if (wp >= 0 && wp < Wn) {      // wave-uniform
                    const h8v a = *(const h8v*)((const char*)xsh + wp * 2048 + laneoff);
                    accS[m] = __builtin_amdgcn_mfma_f32_16x16x32_f16(a, bs, accS[m], 0, 0, 0);
                    accG[m] = __builtin_amdgcn_mfma_f32_16x16x32_f16(a, bg, accG[m], 0, 0, 0);
                }
            }
        }
    }

    // epilogue: D layout col = lane&15 (oc), row = (lane>>4)*4 + r (node)
    const float sbv = sb[node16];
    const float gbv = gb[node16];
    const int oc = G * 16 + node16;
    #pragma unroll
    for (int m = 0; m < 3; ++m) {
        const int w = wv * 3 + m;
        #pragma unroll
        for (int r = 0; r < 4; ++r) {
            const int node = (lane >> 4) * 4 + r;
            const float sv = accS[m][r] + sbv;
            const float gv = accG[m][r] + gbv;
            const float rv = sv > 0.f ? sv : 0.f;
            const float sg = 1.f / (1.f + expf(-gv));
            h[((size_t)w * Nn + nb + node) * Cn + oc] = rv * sg;
        }
    }
    __syncthreads();   // wsh reused by next group
}

// ---------------------------------------------------------------------------
// Inception gated temporal conv, MFMA version. Block = 16 nodes x all 12 w.
// x staged once as fp16 in LDS with XOR swizzle (granule ^= (node&7)<<4) --
// the [node][128B] row layout is otherwise a 16-way bank conflict on the
// 16-lane A-fragment read. LDS 53.2 KB -> 3 blocks/CU.
// ---------------------------------------------------------------------------
__global__ __launch_bounds__(256, 3) void inception_mfma_kernel(
    const float* __restrict__ x,
    const float* __restrict__ sb1, const float* __restrict__ gb1,
    const float* __restrict__ sb3, const float* __restrict__ gb3,
    const float* __restrict__ sb5, const float* __restrict__ gb5,
    const float* __restrict__ sb7, const float* __restrict__ gb7,
    const __half* __restrict__ wT,
    float* __restrict__ h)
{
    __shared__ __align__(16) __half xsh[12 * 16 * 64];   // 24,576 B
    __shared__ __align__(16) __half wsh[14336];           // 28,672 B (max group)
    const int tid = threadIdx.x;
    const int nb  = blockIdx.x * 16;

    const float4* xg = (const float4*)x;
    for (int i = tid; i < 3072; i += 256) {
        const int w = i >> 8, r = i & 255, node = r >> 4, c4 = r & 15;
        const float4 v = xg[((size_t)w * Nn + nb + node) * 16 + c4];
        h4v p = { (_Float16)v.x, (_Float16)v.y, (_Float16)v.z, (_Float16)v.w };
        const int off = w * 2048 + node * 128 + (((c4 << 3)) ^ ((node & 7) << 4));
        *(h4v*)((char*)xsh + off) = p;
    }
    // first __syncthreads inside mfma_group<0> covers x staging too
    mfma_group<0>(wT,         wsh, xsh, sb1, gb1, h, nb, tid);
    mfma_group<1>(wT + 2048,  wsh, xsh, sb3, gb3, h, nb, tid);
    mfma_group<2>(wT + 8192,  wsh, xsh, sb5, gb5, h, nb, tid);
    mfma_group<3>(wT + 18432, wsh, xsh, sb7, gb7, h, nb, tid);
}

// ---------------------------------------------------------------------------
// Per-window (N x 64) @ (64 x 64) matmul, fp32 in -> fp16 out. Tail guarded.
// ---------------------------------------------------------------------------
__global__ __launch_bounds__(256) void matmul_half_kernel(
    const float* __restrict__ h, const float* __restrict__ gw,
    __half* __restrict__ t)
{
    const int w  = blockIdx.y;
    const int nb = blockIdx.x * 64;
    __shared__ float wm[64 * 64];
    __shared__ float hT[64 * 64];
    const int tid = threadIdx.x;

    const float4* wsrc = (const float4*)(gw + (size_t)w * 4096);
    float4* wm4 = (float4*)wm;
    for (int i = tid; i < 1024; i += 256) wm4[i] = wsrc[i];

    {
        const int n = tid >> 2, icq = tid & 3;
        const int nclamp = (nb + n < Nn) ? (nb + n) : (Nn - 1);
        const float4* hsrc = (const float4*)(h + ((size_t)w * Nn + nclamp) * 64);
        #pragma unroll
        for (int k = 0; k < 4; ++k) {
            float4 v = hsrc[icq + 4 * k];
            int ic = (icq + 4 * k) * 4;
            hT[(ic + 0) * 64 + n] = v.x;
            hT[(ic + 1) * 64 + n] = v.y;
            hT[(ic + 2) * 64 + n] = v.z;
            hT[(ic + 3) * 64 + n] = v.w;
        }
    }
    __syncthreads();

    const int oc0 = (tid & 15) * 4;
    const int n0  = (tid >> 4) * 4;
    float acc[4][4] = {{0.f}};
    #pragma unroll
    for (int ic = 0; ic < 64; ++ic) {
        const float4 hv = *(const float4*)&hT[ic * 64 + n0];
        const float4 wv = *(const float4*)&wm[ic * 64 + oc0];
        acc[0][0] = fmaf(hv.x, wv.x, acc[0][0]);
        acc[0][1] = fmaf(hv.x, wv.y, acc[0][1]);
        acc[0][2] = fmaf(hv.x, wv.z, acc[0][2]);
        acc[0][3] = fmaf(hv.x, wv.w, acc[0][3]);
        acc[1][0] = fmaf(hv.y, wv.x, acc[1][0]);
        acc[1][1] = fmaf(hv.y, wv.y, acc[1][1]);
        acc[1][2] = fmaf(hv.y, wv.z, acc[1][2]);
        acc[1][3] = fmaf(hv.y, wv.w, acc[1][3]);
        acc[2][0] = fmaf(hv.z, wv.x, acc[2][0]);
        acc[2][1] = fmaf(hv.z, wv.y, acc[2][1]);
        acc[2][2] = fmaf(hv.z, wv.z, acc[2][2]);
        acc[2][3] = fmaf(hv.z, wv.w, acc[2][3]);
        acc[3][0] = fmaf(hv.w, wv.x, acc[3][0]);
        acc[3][1] = fmaf(hv.w, wv.y, acc[3][1]);
        acc[3][2] = fmaf(hv.w, wv.z, acc[3][2]);
        acc[3][3] = fmaf(hv.w, wv.w, acc[3][3]);
    }

    #pragma unroll
    for (int i = 0; i < 4; ++i) {
        if (nb + n0 + i < Nn) {
            __half2 lo = __floats2half2_rn(acc[i][0], acc[i][1]);
            __half2 hi = __floats2half2_rn(acc[i][2], acc[i][3]);
            uint2 pack;
            pack.x = *(const unsigned int*)&lo;
            pack.y = *(const unsigned int*)&hi;
            *(uint2*)&t[((size_t)w * Nn + nb + n0 + i) * 64 + oc0] = pack;
        }
    }
}

// ---------------------------------------------------------------------------
// Counting-sort preamble.
// ---------------------------------------------------------------------------
__global__ __launch_bounds__(256) void hist_kernel(
    const int* __restrict__ ei, int* __restrict__ deg)
{
    const int w = blockIdx.y;
    const int e = blockIdx.x * 256 + threadIdx.x;
    const int dst = ei[(size_t)w * 2 * En + En + e];
    atomicAdd(&deg[w * Nn + dst], 1);
}

// 12 blocks x 1024 threads: hierarchical scan (was 12 waves on the whole GPU).
__global__ __launch_bounds__(1024) void scan_kernel(
    const int* __restrict__ deg, int* __restrict__ offs, int* __restrict__ curs)
{
    const int w   = blockIdx.x;
    const int tid = threadIdx.x;
    const int lane = tid & 63;
    const int wv   = tid >> 6;            // 0..15
    __shared__ int wsum[16];
    __shared__ int ctot;
    int running = 0;
    for (int base = 0; base < Nn; base += 1024) {
        const int i = base + tid;
        int v = (i < Nn) ? deg[w * Nn + i] : 0;
        int sum = v;
        #pragma unroll
        for (int d = 1; d < 64; d <<= 1) {
            int t = __shfl_up(sum, d);
            if (lane >= d) sum += t;
        }
        if (lane == 63) wsum[wv] = sum;
        __syncthreads();
        if (tid < 16) {
            int orig = wsum[tid];
            int s = orig;
            #pragma unroll
            for (int d = 1; d < 16; d <<= 1) {
                int t = __shfl_up(s, d);
                if (tid >= d) s += t;
            }
            wsum[tid] = s - orig;         // exclusive across waves
            if (tid == 15) ctot = s;
        }
        __syncthreads();
        if (i < Nn) {
            const int e = running + wsum[wv] + (sum - v);
            offs[w * OFFS_STRIDE + i] = e;
            curs[w * Nn + i] = e;
        }
        running += ctot;
        __syncthreads();
    }
    if (tid == 0) offs[w * OFFS_STRIDE + Nn] = running;
}

// XCD-affinity swizzle: all blocks of window w share b%8 (1D grid, 15000).
__global__ __launch_bounds__(256) void sortpairs_kernel(
    const int* __restrict__ ei, const float* __restrict__ ew,
    int* __restrict__ curs, float2* __restrict__ pairs)
{
    const int b = blockIdx.x;
    const int r = b & 7, q = b >> 3;
    int w, eg;
    if (q < 1250) { w = r; eg = q; }
    else { int q2 = q - 1250; w = 8 + (r >> 1); eg = q2 * 2 + (r & 1); }
    const int e = eg * 256 + threadIdx.x;
    const int* eis = ei + (size_t)w * 2 * En;
    const int src = eis[e];
    const int dst = eis[En + e];
    const float wt = ew[(size_t)w * En + e];
    const int pos = atomicAdd(&curs[w * Nn + dst], 1);
    pairs[(size_t)w * En + pos] = make_float2(__int_as_float(src), wt);
}

// ---------------------------------------------------------------------------
// Aggregation: one wave per dst; 2 edges in flight (32 lanes x __half2 each,
// 128 B/edge in half the instructions). XCD-affinity swizzle: blocks of
// window w land on b%8=f(w) -> each XCD's L2 holds <=2 t-slabs (5 MB) instead
// of all 12 (31 MB thrash).
// ---------------------------------------------------------------------------
template<bool LAST>
__global__ __launch_bounds__(256) void agg_kernel(
    const __half* __restrict__ t, const float2* __restrict__ pairs,
    const int* __restrict__ offs, const float* __restrict__ b,
    const float* __restrict__ x, float* __restrict__ out)
{
    const int blk = blockIdx.x;
    const int r = blk & 7, q = blk >> 3;
    int w, ng;
    if (q < 5000) { w = r; ng = q; }
    else { int q2 = q - 5000; w = 8 + (r >> 1); ng = q2 * 2 + (r & 1); }

    const int d    = ng * 4 + (threadIdx.x >> 6);
    const int lane = threadIdx.x & 63;
    const int hgrp = lane >> 5;           // which of 2 concurrent edges
    const int c    = lane & 31;           // channel pair index
    const int* ow  = offs + w * OFFS_STRIDE;
    const int beg = ow[d];
    const int end = ow[d + 1];
    const float2* pw = pairs + (size_t)w * En;
    const __half* tw = t + (size_t)w * Nn * Cn;

    float ax = 0.f, ay = 0.f;
    int i = beg;
    for (; i + 4 <= end; i += 4) {
        float2 p0 = pw[i + hgrp];
        float2 p1 = pw[i + 2 + hgrp];
        float2 f0 = __half22float2(*(const __half2*)&tw[(size_t)__float_as_int(p0.x) * Cn + 2 * c]);
        float2 f1 = __half22float2(*(const __half2*)&tw[(size_t)__float_as_int(p1.x) * Cn + 2 * c]);
        ax = fmaf(p0.y, f0.x, ax);
        ay = fmaf(p0.y, f0.y, ay);
        ax = fmaf(p1.y, f1.x, ax);
        ay = fmaf(p1.y, f1.y, ay);
    }
    if (i + 2 <= end) {
        float2 p0 = pw[i + hgrp];
        float2 f0 = __half22float2(*(const __half2*)&tw[(size_t)__float_as_int(p0.x) * Cn + 2 * c]);
        ax = fmaf(p0.y, f0.x, ax);
        ay = fmaf(p0.y, f0.y, ay);
        i += 2;
    }
    if (i < end && hgrp == 0) {
        float2 p0 = pw[i];
        float2 f0 = __half22float2(*(const __half2*)&tw[(size_t)__float_as_int(p0.x) * Cn + 2 * c]);
        ax = fmaf(p0.y, f0.x, ax);
        ay = fmaf(p0.y, f0.y, ay);
    }

    ax += __shfl_xor(ax, 32);
    ay += __shfl_xor(ay, 32);

    if (hgrp == 0) {
        const float2 bv = *(const float2*)&b[w * Cn + 2 * c];
        float vx = elu_f(ax + bv.x);
        float vy = elu_f(ay + bv.y);
        const size_t oi = ((size_t)w * Nn + d) * Cn + 2 * c;
        if (LAST) {
            const float2 xv = *(const float2*)&x[oi];
            vx += xv.x;
            vy += xv.y;
        }
        *(float2*)&out[oi] = make_float2(vx, vy);
    }
}

// ---------------------------------------------------------------------------
// ws layout (floats):
//   [0)          pairs : 7,680,000
//   [7,680,000)  offs  :   240,384 (int)
//   [7,920,384)  curs  :   240,000 (int)
//   [8,160,384)  deg   :   240,000 (int)  -- reused as wT (32768 halfs) after scan
//   [8,400,384)  H     : 15,360,000
// t (fp16) lives in d_out between matmul and agg; final result built in H,
// then copied to d_out.
// ---------------------------------------------------------------------------
extern "C" void kernel_launch(void* const* d_in, const int* in_sizes, int n_in,
                              void* d_out, int out_size, void* d_ws, size_t ws_size,
                              hipStream_t stream)
{
    const float* x    = (const float*)d_in[0];
    const int*   ei   = (const int*)d_in[1];
    const float* ew   = (const float*)d_in[2];
    const float* sw1  = (const float*)d_in[3];
    const float* sb1  = (const float*)d_in[4];
    const float* gw1  = (const float*)d_in[5];
    const float* gb1  = (const float*)d_in[6];
    const float* sw3  = (const float*)d_in[7];
    const float* sb3  = (const float*)d_in[8];
    const float* gw3  = (const float*)d_in[9];
    const float* gb3  = (const float*)d_in[10];
    const float* sw5  = (const float*)d_in[11];
    const float* sb5  = (const float*)d_in[12];
    const float* gw5  = (const float*)d_in[13];
    const float* gb5  = (const float*)d_in[14];
    const float* sw7  = (const float*)d_in[15];
    const float* sb7  = (const float*)d_in[16];
    const float* gw7  = (const float*)d_in[17];
    const float* gb7  = (const float*)d_in[18];
    const float* gcnw = (const float*)d_in[19];
    const float* gcnb = (const float*)d_in[20];
    float* out = (float*)d_out;
    __half* Th = (__half*)d_out;

    const size_t WNC = (size_t)Wn * Nn * Cn;
    const int mm_grid = (Nn + 63) / 64;    // 313 — tail block guarded

    float2* pairs = (float2*)d_ws;
    int*    offs  = (int*)((float*)d_ws + 7680000);
    int*    curs  = offs + 240384;
    int*    deg   = curs + 240000;
    __half* wT    = (__half*)deg;          // reused after scan_kernel
    float*  H     = (float*)(deg + 240000);

    // --- sort preamble ---
    hipMemsetAsync(deg, 0, (size_t)Wn * Nn * sizeof(int), stream);
    hist_kernel<<<dim3(En / 256, Wn), 256, 0, stream>>>(ei, deg);
    scan_kernel<<<Wn, 1024, 0, stream>>>(deg, offs, curs);        // last read of deg
    sortpairs_kernel<<<15000, 256, 0, stream>>>(ei, ew, curs, pairs);

    // --- weight fragment pack (fp16) into the dead deg region ---
    wprep_kernel<<<128, 256, 0, stream>>>(sw1, gw1, sw3, gw3, sw5, gw5, sw7, gw7, wT);

    // --- feature path (MFMA) ---
    inception_mfma_kernel<<<Nn / 16, 256, 0, stream>>>(
        x, sb1, gb1, sb3, gb3, sb5, gb5, sb7, gb7, wT, H);

    // hop 0
    matmul_half_kernel<<<dim3(mm_grid, Wn), 256, 0, stream>>>(H, gcnw, Th);
    agg_kernel<false><<<60000, 256, 0, stream>>>(
        Th, pairs, offs, gcnb, nullptr, H);

    // hop 1
    matmul_half_kernel<<<dim3(mm_grid, Wn), 256, 0, stream>>>(
        H, gcnw + (size_t)Wn * Cn * Cn, Th);
    agg_kernel<true><<<60000, 256, 0, stream>>>(
        Th, pairs, offs, gcnb + (size_t)Wn * Cn, x, H);
    hipMemcpyAsync(out, H, WNC * sizeof(float), hipMemcpyDeviceToDevice, stream);
}